// Round 3
// baseline (592.400 us; speedup 1.0000x reference)
//
#include <hip/hip_runtime.h>
#include <stdint.h>

typedef __attribute__((ext_vector_type(8))) short short8;
typedef __attribute__((ext_vector_type(4))) float f32x4;

#define DEV __device__ __forceinline__

DEV unsigned short f2bf(float f) {
    unsigned int u = __float_as_uint(f);
    u += 0x7FFFu + ((u >> 16) & 1u);   // round-to-nearest-even
    return (unsigned short)(u >> 16);
}

DEV void gload_lds16(const void* g, void* l) {
    // async global->LDS, 16B per lane. LDS dest is wave-uniform base (+lane*16 by HW).
    __builtin_amdgcn_global_load_lds(
        (const __attribute__((address_space(1))) unsigned int*)g,
        (__attribute__((address_space(3))) unsigned int*)l,
        16, 0, 0);
}

// ---------------------------------------------------------------- converts
__global__ __launch_bounds__(256) void f32_to_bf16_k(
    const float* __restrict__ in, unsigned short* __restrict__ out, int n8) {
    int i = blockIdx.x * 256 + threadIdx.x;
    if (i >= n8) return;
    const float4* src = (const float4*)in + (size_t)i * 2;
    float4 a = src[0], b = src[1];
    short8 o;
    o[0] = f2bf(a.x); o[1] = f2bf(a.y); o[2] = f2bf(a.z); o[3] = f2bf(a.w);
    o[4] = f2bf(b.x); o[5] = f2bf(b.y); o[6] = f2bf(b.z); o[7] = f2bf(b.w);
    *((short8*)out + i) = o;
}

// build x_bf16 [8192][3072] from the six [4,2048,512] f32 inputs
__global__ __launch_bounds__(256) void pack_x_k(
    const float* __restrict__ p0, const float* __restrict__ p1,
    const float* __restrict__ p2, const float* __restrict__ p3,
    const float* __restrict__ p4, const float* __restrict__ p5,
    unsigned short* __restrict__ x) {
    int i = blockIdx.x * 256 + threadIdx.x;   // 3145728 threads
    int e0 = i * 8;
    int m = e0 / 3072;
    int k = e0 - m * 3072;
    int sel = k >> 9;
    const float* src;
    switch (sel) {
        case 0: src = p0; break; case 1: src = p1; break;
        case 2: src = p2; break; case 3: src = p3; break;
        case 4: src = p4; break; default: src = p5; break;
    }
    src += (size_t)m * 512 + (k & 511);
    float4 a = *(const float4*)src;
    float4 b = *(const float4*)(src + 4);
    short8 o;
    o[0] = f2bf(a.x); o[1] = f2bf(a.y); o[2] = f2bf(a.z); o[3] = f2bf(a.w);
    o[4] = f2bf(b.x); o[5] = f2bf(b.y); o[6] = f2bf(b.z); o[7] = f2bf(b.w);
    *(short8*)(x + e0) = o;
}

// ---------------------------------------------------------------- mask scan
// Parallel: one 64-thread block per (s, qb); lanes 0..31 test one 64x64 block
// corner each (mask is block-constant); ballot + popcount-prefix compaction.
__global__ void scan_masks_k(const void* mr, const void* mi,
                             int* __restrict__ nact, unsigned char* __restrict__ lists) {
    int blk = blockIdx.x;            // 64 = 2 streams x 32 qb
    int s = blk >> 5, qb = blk & 31;
    int lane = threadIdx.x;
    const unsigned char* det = (const unsigned char*)mr;
    bool is_byte = det[1] != 0;      // bool-byte vs 4-byte storage
    const void* m = s ? mi : mr;
    bool on = false;
    if (lane < 32) {
        size_t off = (size_t)(qb * 64) * 2048 + (size_t)lane * 64;
        on = is_byte ? (((const unsigned char*)m)[off] != 0)
                     : (((const int*)m)[off] != 0);
    }
    unsigned long long mask = __ballot(on);
    if (on) {
        int pos = __popcll(mask & ((1ull << lane) - 1ull));
        lists[blk * 32 + pos] = (unsigned char)lane;
    }
    if (lane == 0) nact[blk] = (int)__popcll(mask);
}

// ---------------------------------------------------------------- 8-phase GEMM (B^T)
// C[m,n] = sum_k A[m,k]*B[n,k] + bias[n].  A:[M][K] bf16, B:[N][K] bf16.
// BM=256, BN=NF*64 (NF=4 -> 256, NF=3 -> 192), BK=64, 512 threads (8 waves,
// 2Mx4N; wave tile 128 x NF*16). 2 K-tiles/iter, 8 phases; A staged as 4
// chunks, B as NF chunks; counted vmcnt(NF) only at phases 3/7 (never 0).
// LDS st-swizzle byte ^= ((row&7)<<4) on BOTH pre-swizzled global source of
// global_load_lds and the ds_read address (rule 21).

#define MFMA_TILE(mbase)                                                       \
    do {                                                                       \
        _Pragma("unroll")                                                      \
        for (int m_ = 0; m_ < 4; ++m_) {                                       \
            _Pragma("unroll")                                                  \
            for (int n_ = 0; n_ < NF; ++n_)                                    \
                acc[(mbase) + m_][n_] = __builtin_amdgcn_mfma_f32_16x16x32_bf16( \
                    af[m_], bf[n_], acc[(mbase) + m_][n_], 0, 0, 0);           \
        }                                                                      \
    } while (0)

#define PHASE_PRE()                                          \
    __builtin_amdgcn_s_barrier();                            \
    asm volatile("s_waitcnt lgkmcnt(0)" ::: "memory");       \
    __builtin_amdgcn_sched_barrier(0);                       \
    __builtin_amdgcn_s_setprio(1)

#define PHASE_END()                                          \
    __builtin_amdgcn_s_setprio(0);                           \
    __builtin_amdgcn_s_barrier();                            \
    asm volatile("" ::: "memory")

#define WAIT_VN()                                                          \
    do {                                                                   \
        if constexpr (NF == 3) asm volatile("s_waitcnt vmcnt(3)" ::: "memory"); \
        else asm volatile("s_waitcnt vmcnt(4)" ::: "memory");              \
    } while (0)

#define PHASE_END_VN()                                       \
    __builtin_amdgcn_s_setprio(0);                           \
    WAIT_VN();                                               \
    __builtin_amdgcn_s_barrier();                            \
    asm volatile("" ::: "memory")

template <int MODE, int NF>
__global__ __launch_bounds__(512, 2) void gemm256(
    const unsigned short* __restrict__ A, const unsigned short* __restrict__ B,
    const float* __restrict__ bias, unsigned short* __restrict__ Cb,
    float* __restrict__ Cf, int M, int N, int K, int NBN, int halfN, int half_elems) {
    constexpr int BN = NF * 64;
    __shared__ unsigned short lds[2][16384 + NF * 4096];  // [buf][A 32KB | B NF*8KB]
    const int tid = threadIdx.x;
    const int wv = tid >> 6, ln = tid & 63;
    const int fr = ln & 15, fo = ln >> 4;
    const int wr = wv >> 2, wc = wv & 3;
    // XCD-aware swizzle (gridDim.x % 8 == 0 for both call sites)
    const int cpx = gridDim.x >> 3;
    const int wgid = (blockIdx.x & 7) * cpx + (blockIdx.x >> 3);
    const int bm = wgid / NBN, bn = wgid % NBN;
    const unsigned short* Abase = A + (size_t)(bm * 256) * K;
    const unsigned short* Bbase = B + (size_t)(bn * BN) * K;
    const int NT = K >> 6;
    const int NI = NT >> 1;

    auto stagePair = [&](int buf, int isB, int t) {
        const unsigned short* G = isB ? Bbase : Abase;
        unsigned short* Ld = &lds[buf][isB ? 16384 : 0];
        const int kcol = t * 64;
        const int nch = isB ? NF : 4;
        #pragma unroll
        for (int r2 = 0; r2 < nch; ++r2) {
            int d = r2 * 8192 + wv * 1024 + ln * 16;        // linear dest byte
            int sw = d ^ (((d >> 7) & 7) << 4);             // pre-swizzled source
            int grow = sw >> 7;
            int gcol = (sw & 127) >> 1;
            gload_lds16(G + (size_t)grow * K + kcol + gcol,
                        (char*)Ld + r2 * 8192 + wv * 1024);
        }
    };
    auto readA = [&](int buf, int mh, int ks, short8* dst) {
        #pragma unroll
        for (int m = 0; m < 4; ++m) {
            int row = wr * 128 + mh * 64 + m * 16 + fr;
            int byte = (row * 128 + ks * 64 + fo * 16) ^ ((row & 7) << 4);
            dst[m] = *(const short8*)((const char*)&lds[buf][0] + byte);
        }
    };
    auto readB = [&](int buf, int ks, short8* dst) {
        #pragma unroll
        for (int n = 0; n < NF; ++n) {
            int row = wc * (NF * 16) + n * 16 + fr;
            int byte = (row * 128 + ks * 64 + fo * 16) ^ ((row & 7) << 4);
            dst[n] = *(const short8*)((const char*)&lds[buf][16384] + byte);
        }
    };

    f32x4 acc[8][NF];
    #pragma unroll
    for (int m = 0; m < 8; ++m)
        #pragma unroll
        for (int n = 0; n < NF; ++n) acc[m][n] = f32x4{0.f, 0.f, 0.f, 0.f};

    // prologue: buf0 <- tile0 (A+B), buf1.B <- tile1
    stagePair(0, 0, 0);
    stagePair(0, 1, 0);
    stagePair(1, 1, 1);
    WAIT_VN();
    __builtin_amdgcn_s_barrier();
    asm volatile("" ::: "memory");

    for (int i = 0; i < NI; ++i) {
        const int t1 = 2 * i + 1;
        const int tn0 = (2 * i + 2) % NT;
        const int tn1 = (2 * i + 3) % NT;
        short8 af[4], bf[4];
        // p0: compute buf0 (mh0,ks0); stage buf1.A <- t1 (used at p4)
        readA(0, 0, 0, af); readB(0, 0, bf);
        stagePair(1, 0, t1);
        PHASE_PRE(); MFMA_TILE(0); PHASE_END();
        // p1: (mh1,ks0)
        readA(0, 1, 0, af);
        PHASE_PRE(); MFMA_TILE(4); PHASE_END();
        // p2: (mh0,ks1)
        readA(0, 0, 1, af); readB(0, 1, bf);
        PHASE_PRE(); MFMA_TILE(0); PHASE_END();
        // p3: (mh1,ks1); stage buf0.B <- tn0; drain prev buf1.B + p0's buf1.A
        readA(0, 1, 1, af);
        stagePair(0, 1, tn0);
        PHASE_PRE(); MFMA_TILE(4); PHASE_END_VN();
        // p4: compute buf1 (mh0,ks0); stage buf0.A <- tn0
        readA(1, 0, 0, af); readB(1, 0, bf);
        stagePair(0, 0, tn0);
        PHASE_PRE(); MFMA_TILE(0); PHASE_END();
        // p5: (mh1,ks0)
        readA(1, 1, 0, af);
        PHASE_PRE(); MFMA_TILE(4); PHASE_END();
        // p6: (mh0,ks1)
        readA(1, 0, 1, af); readB(1, 1, bf);
        PHASE_PRE(); MFMA_TILE(0); PHASE_END();
        // p7: (mh1,ks1); stage buf1.B <- tn1; drain p3's buf0.B + p4's buf0.A
        readA(1, 1, 1, af);
        stagePair(1, 1, tn1);
        PHASE_PRE(); MFMA_TILE(4); PHASE_END_VN();
    }

    #pragma unroll
    for (int mi = 0; mi < 8; ++mi)
        #pragma unroll
        for (int ni = 0; ni < NF; ++ni)
            #pragma unroll
            for (int j = 0; j < 4; ++j) {
                int gr = bm * 256 + wr * 128 + mi * 16 + fo * 4 + j;
                int gc = bn * BN + wc * (NF * 16) + ni * 16 + fr;
                float v = acc[mi][ni][j] + bias[gc];
                if (MODE == 0) {
                    Cb[(size_t)gr * N + gc] = f2bf(v);
                } else {
                    if (gc < halfN) Cf[(size_t)gr * halfN + gc] = v;
                    else Cf[half_elems + (size_t)gr * halfN + (gc - halfN)] = v;
                }
            }
}

// ---------------------------------------------------------------- V transpose
// Vt[s][b][dcol][krow] <- qkv[b*2048+krow][2048 + s*512 + dcol]
__global__ __launch_bounds__(256) void transpose_v_k(
    const unsigned short* __restrict__ qkv, unsigned short* __restrict__ Vt) {
    int idx = blockIdx.x;
    int kt = idx & 31; idx >>= 5;
    int dt = idx & 7;  idx >>= 3;
    int b  = idx & 3;  idx >>= 2;
    int s  = idx;
    __shared__ unsigned short tile[64][65];
    int t = threadIdx.x;
    int r = t >> 2;
    int cs = (t & 3) * 16;
    const unsigned short* src =
        qkv + (size_t)(b * 2048 + kt * 64 + r) * 3072 + 2048 + s * 512 + dt * 64 + cs;
    short8 v0 = *(const short8*)src;
    short8 v1 = *(const short8*)(src + 8);
    #pragma unroll
    for (int i = 0; i < 8; ++i) { tile[r][cs + i] = v0[i]; tile[r][cs + 8 + i] = v1[i]; }
    __syncthreads();
    short8 o0, o1;
    #pragma unroll
    for (int i = 0; i < 8; ++i) { o0[i] = tile[cs + i][r]; o1[i] = tile[cs + 8 + i][r]; }
    unsigned short* dst =
        Vt + (size_t)((s * 4 + b) * 512 + dt * 64 + r) * 2048 + kt * 64 + cs;
    *(short8*)dst = o0;
    *(short8*)(dst + 8) = o1;
}

// ---------------------------------------------------------------- attention
// One 64-thread WG per (b, s, qb, quarter16, dhalf256): 2048 WGs -> 8 WGs/CU
// (2 waves/SIMD). acc covers 16 q-rows x 256 d-cols (64 VGPR); QK^T over full
// d=512 duplicated across the two dhalf waves (K block is L2-resident).
// Bounded unrolls keep VGPR < 256 (no spill).
__global__ __launch_bounds__(64, 2) void attn_k(
    const unsigned short* __restrict__ qkv, const unsigned short* __restrict__ Vt,
    unsigned short* __restrict__ attn, const int* __restrict__ nact,
    const unsigned char* __restrict__ lists) {
    int wg = blockIdx.x;
    int xcd = wg & 7, idx = wg >> 3;          // XCD holds one (b,s) K/V set
    int b = xcd >> 1, s = xcd & 1;
    int qb = idx >> 3, quarter = (idx >> 1) & 3, dh = idx & 1;
    int lane = threadIdx.x;
    int fr = lane & 15, fo = lane >> 4;
    const float scale = 0.04419417382415922f;  // 1/sqrt(512)
    __shared__ unsigned short Pl[1024];
    unsigned char* Plb = (unsigned char*)&Pl[0];

    int qoff = s * 512, koff = 1024 + s * 512;
    size_t vtbase = (size_t)((s * 4 + b) * 512 + dh * 256) * 2048;
    int mrow = b * 2048 + qb * 64 + quarter * 16;

    short8 qf[16];
    const unsigned short* qrow_ptr = qkv + (size_t)(mrow + fr) * 3072 + qoff + fo * 8;
    #pragma unroll
    for (int kk = 0; kk < 16; ++kk) qf[kk] = *(const short8*)(qrow_ptr + kk * 32);

    f32x4 acc[16];
    #pragma unroll
    for (int di = 0; di < 16; ++di) acc[di] = f32x4{0.f, 0.f, 0.f, 0.f};
    float mr[4] = {-1e30f, -1e30f, -1e30f, -1e30f};
    float lr[4] = {0.f, 0.f, 0.f, 0.f};

    int na = nact[s * 32 + qb];
    const unsigned char* lst = lists + (s * 32 + qb) * 32;

    for (int t = 0; t < na; ++t) {
        int kb = lst[t];
        const unsigned short* kbp =
            qkv + (size_t)(b * 2048 + kb * 64 + fr) * 3072 + koff + fo * 8;
        f32x4 sf[4];
        #pragma unroll
        for (int nf = 0; nf < 4; ++nf) sf[nf] = f32x4{0.f, 0.f, 0.f, 0.f};
        // kk-outer / nf-inner: 4 independent MFMA chains, 4 loads per step
        #pragma unroll 4
        for (int kk = 0; kk < 16; ++kk) {
            short8 k0 = *(const short8*)(kbp + kk * 32);
            short8 k1 = *(const short8*)(kbp + (size_t)16 * 3072 + kk * 32);
            short8 k2 = *(const short8*)(kbp + (size_t)32 * 3072 + kk * 32);
            short8 k3 = *(const short8*)(kbp + (size_t)48 * 3072 + kk * 32);
            sf[0] = __builtin_amdgcn_mfma_f32_16x16x32_bf16(qf[kk], k0, sf[0], 0, 0, 0);
            sf[1] = __builtin_amdgcn_mfma_f32_16x16x32_bf16(qf[kk], k1, sf[1], 0, 0, 0);
            sf[2] = __builtin_amdgcn_mfma_f32_16x16x32_bf16(qf[kk], k2, sf[2], 0, 0, 0);
            sf[3] = __builtin_amdgcn_mfma_f32_16x16x32_bf16(qf[kk], k3, sf[3], 0, 0, 0);
        }
        #pragma unroll
        for (int nf = 0; nf < 4; ++nf) sf[nf] *= scale;
        float bm[4], f_[4], rs[4];
        #pragma unroll
        for (int j = 0; j < 4; ++j) {
            float v = fmaxf(fmaxf(sf[0][j], sf[1][j]), fmaxf(sf[2][j], sf[3][j]));
            #pragma unroll
            for (int off = 1; off < 16; off <<= 1) v = fmaxf(v, __shfl_xor(v, off, 64));
            bm[j] = v;
        }
        #pragma unroll
        for (int j = 0; j < 4; ++j) {
            float mn = fmaxf(mr[j], bm[j]);
            f_[j] = __expf(mr[j] - mn);
            mr[j] = mn;
            rs[j] = 0.f;
        }
        #pragma unroll
        for (int nf = 0; nf < 4; ++nf)
            #pragma unroll
            for (int j = 0; j < 4; ++j) {
                float p = __expf(sf[nf][j] - mr[j]);
                sf[nf][j] = p;
                rs[j] += p;
            }
        #pragma unroll
        for (int j = 0; j < 4; ++j) {
            float v = rs[j];
            #pragma unroll
            for (int off = 1; off < 16; off <<= 1) v += __shfl_xor(v, off, 64);
            lr[j] = lr[j] * f_[j] + v;
        }
        #pragma unroll
        for (int di = 0; di < 16; ++di) {
            acc[di][0] *= f_[0]; acc[di][1] *= f_[1];
            acc[di][2] *= f_[2]; acc[di][3] *= f_[3];
        }
        // P -> LDS (bf16), XOR-swizzled
        #pragma unroll
        for (int nf = 0; nf < 4; ++nf)
            #pragma unroll
            for (int j = 0; j < 4; ++j) {
                int row = fo * 4 + j, col = nf * 16 + fr;
                int byte = row * 128 + ((col * 2) ^ ((row & 7) << 4));
                *(unsigned short*)(Plb + byte) = f2bf(sf[nf][j]);
            }
        asm volatile("s_waitcnt lgkmcnt(0)" ::: "memory");
        // PV over this wave's 256 d-cols
        #pragma unroll
        for (int ks = 0; ks < 2; ++ks) {
            int rbyte = fr * 128 + (((ks * 32 + fo * 8) * 2) ^ ((fr & 7) << 4));
            short8 pf = *(const short8*)(Plb + rbyte);
            const unsigned short* vp =
                Vt + vtbase + (size_t)fr * 2048 + kb * 64 + ks * 32 + fo * 8;
            #pragma unroll 4
            for (int di = 0; di < 16; ++di) {
                short8 vf = *(const short8*)(vp + (size_t)di * 16 * 2048);
                acc[di] = __builtin_amdgcn_mfma_f32_16x16x32_bf16(pf, vf, acc[di], 0, 0, 0);
            }
        }
    }
    float inv[4];
    #pragma unroll
    for (int j = 0; j < 4; ++j) inv[j] = 1.0f / lr[j];
    unsigned short* orow = attn + (size_t)(mrow + fo * 4) * 1024 + s * 512 + dh * 256 + fr;
    #pragma unroll
    for (int di = 0; di < 16; ++di)
        #pragma unroll
        for (int j = 0; j < 4; ++j)
            orow[(size_t)j * 1024 + di * 16] = f2bf(acc[di][j] * inv[j]);
}

// ---------------------------------------------------------------- launch
extern "C" void kernel_launch(void* const* d_in, const int* in_sizes, int n_in,
                              void* d_out, int out_size, void* d_ws, size_t ws_size,
                              hipStream_t stream) {
    const float* q_r = (const float*)d_in[0];
    const float* q_i = (const float*)d_in[1];
    const float* k_r = (const float*)d_in[2];
    const float* k_i = (const float*)d_in[3];
    const float* v_r = (const float*)d_in[4];
    const float* v_i = (const float*)d_in[5];
    const float* W_qkv = (const float*)d_in[6];
    const float* b_qkv = (const float*)d_in[7];
    const float* W_out = (const float*)d_in[8];
    const float* b_out = (const float*)d_in[9];
    const void* mask_r = d_in[10];
    const void* mask_i = d_in[11];

    char* ws = (char*)d_ws;
    unsigned short* x    = (unsigned short*)(ws);                  // 50331648 B
    unsigned short* Wq   = (unsigned short*)(ws + 50331648);       // 18874368 B
    unsigned short* qkv  = (unsigned short*)(ws + 69206016);       // 50331648 B
    unsigned short* Wo   = (unsigned short*)(ws + 119537664);      //  2097152 B
    int* nact            = (int*)(ws + 121634816);                 //   256 B
    unsigned char* lists = (unsigned char*)(ws + 121634816 + 256); //  2048 B
    // x region is dead after GEMM1 -> reuse for Vt and attn
    unsigned short* Vt   = x;                                      // 16777216 B
    unsigned short* attn = x + 8388608;                            // 16777216 B

    f32_to_bf16_k<<<4608, 256, 0, stream>>>(W_qkv, Wq, 1179648);
    f32_to_bf16_k<<<512, 256, 0, stream>>>(W_out, Wo, 131072);
    pack_x_k<<<12288, 256, 0, stream>>>(q_r, q_i, k_r, k_i, v_r, v_i, x);
    scan_masks_k<<<64, 64, 0, stream>>>(mask_r, mask_i, nact, lists);
    gemm256<0, 3><<<512, 512, 0, stream>>>(x, Wq, b_qkv, qkv, nullptr,
                                           8192, 3072, 3072, 16, 0, 0);
    transpose_v_k<<<2048, 256, 0, stream>>>(qkv, Vt);
    attn_k<<<2048, 64, 0, stream>>>(qkv, Vt, attn, nact, lists);
    gemm256<1, 4><<<128, 512, 0, stream>>>(attn, Wo, b_out, nullptr, (float*)d_out,
                                           8192, 1024, 1024, 4, 512, 4194304);
}

// Round 5
// 474.714 us; speedup vs baseline: 1.2479x; 1.2479x over previous
//
#include <hip/hip_runtime.h>
#include <stdint.h>

typedef __attribute__((ext_vector_type(8))) short short8;
typedef __attribute__((ext_vector_type(4))) float f32x4;

#define DEV __device__ __forceinline__

DEV unsigned short f2bf(float f) {
    unsigned int u = __float_as_uint(f);
    u += 0x7FFFu + ((u >> 16) & 1u);   // round-to-nearest-even
    return (unsigned short)(u >> 16);
}

DEV void gload_lds16(const void* g, void* l) {
    // async global->LDS, 16B per lane. LDS dest is wave-uniform base (+lane*16 by HW).
    __builtin_amdgcn_global_load_lds(
        (const __attribute__((address_space(1))) unsigned int*)g,
        (__attribute__((address_space(3))) unsigned int*)l,
        16, 0, 0);
}

// ---------------------------------------------------------------- converts
__global__ __launch_bounds__(256) void f32_to_bf16_k(
    const float* __restrict__ in, unsigned short* __restrict__ out, int n8) {
    int i = blockIdx.x * 256 + threadIdx.x;
    if (i >= n8) return;
    const float4* src = (const float4*)in + (size_t)i * 2;
    float4 a = src[0], b = src[1];
    short8 o;
    o[0] = f2bf(a.x); o[1] = f2bf(a.y); o[2] = f2bf(a.z); o[3] = f2bf(a.w);
    o[4] = f2bf(b.x); o[5] = f2bf(b.y); o[6] = f2bf(b.z); o[7] = f2bf(b.w);
    *((short8*)out + i) = o;
}

// build x_bf16 [8192][3072] from the six [4,2048,512] f32 inputs
__global__ __launch_bounds__(256) void pack_x_k(
    const float* __restrict__ p0, const float* __restrict__ p1,
    const float* __restrict__ p2, const float* __restrict__ p3,
    const float* __restrict__ p4, const float* __restrict__ p5,
    unsigned short* __restrict__ x) {
    int i = blockIdx.x * 256 + threadIdx.x;   // 3145728 threads
    int e0 = i * 8;
    int m = e0 / 3072;
    int k = e0 - m * 3072;
    int sel = k >> 9;
    const float* src;
    switch (sel) {
        case 0: src = p0; break; case 1: src = p1; break;
        case 2: src = p2; break; case 3: src = p3; break;
        case 4: src = p4; break; default: src = p5; break;
    }
    src += (size_t)m * 512 + (k & 511);
    float4 a = *(const float4*)src;
    float4 b = *(const float4*)(src + 4);
    short8 o;
    o[0] = f2bf(a.x); o[1] = f2bf(a.y); o[2] = f2bf(a.z); o[3] = f2bf(a.w);
    o[4] = f2bf(b.x); o[5] = f2bf(b.y); o[6] = f2bf(b.z); o[7] = f2bf(b.w);
    *(short8*)(x + e0) = o;
}

// ---------------------------------------------------------------- mask scan
__global__ void scan_masks_k(const void* mr, const void* mi,
                             int* __restrict__ nact, unsigned char* __restrict__ lists) {
    int blk = blockIdx.x;            // 64 = 2 streams x 32 qb
    int s = blk >> 5, qb = blk & 31;
    int lane = threadIdx.x;
    const unsigned char* det = (const unsigned char*)mr;
    bool is_byte = det[1] != 0;      // bool-byte vs 4-byte storage
    const void* m = s ? mi : mr;
    bool on = false;
    if (lane < 32) {
        size_t off = (size_t)(qb * 64) * 2048 + (size_t)lane * 64;
        on = is_byte ? (((const unsigned char*)m)[off] != 0)
                     : (((const int*)m)[off] != 0);
    }
    unsigned long long mask = __ballot(on);
    if (on) {
        int pos = __popcll(mask & ((1ull << lane) - 1ull));
        lists[blk * 32 + pos] = (unsigned char)lane;
    }
    if (lane == 0) nact[blk] = (int)__popcll(mask);
}

// ---------------------------------------------------------------- 8-phase GEMM (B^T)
// C[m,n] = sum_k A[m,k]*B[n,k] + bias[n].  BM=256, BN=NF*64, BK=64,
// 512 threads (8 waves, 2Mx4N; wave tile 128 x NF*16). 2 K-tiles/iter,
// 8 phases; A staged as 4 chunks, B as NF; counted vmcnt(NF) at p3/p7 only.
// LDS st-swizzle byte ^= ((row&7)<<4) on BOTH pre-swizzled global source of
// global_load_lds and the ds_read address (rule 21).

#define MFMA_TILE(mbase)                                                       \
    do {                                                                       \
        _Pragma("unroll")                                                      \
        for (int m_ = 0; m_ < 4; ++m_) {                                       \
            _Pragma("unroll")                                                  \
            for (int n_ = 0; n_ < NF; ++n_)                                    \
                acc[(mbase) + m_][n_] = __builtin_amdgcn_mfma_f32_16x16x32_bf16( \
                    af[m_], bf[n_], acc[(mbase) + m_][n_], 0, 0, 0);           \
        }                                                                      \
    } while (0)

#define PHASE_PRE()                                          \
    __builtin_amdgcn_s_barrier();                            \
    asm volatile("s_waitcnt lgkmcnt(0)" ::: "memory");       \
    __builtin_amdgcn_sched_barrier(0);                       \
    __builtin_amdgcn_s_setprio(1)

#define PHASE_END()                                          \
    __builtin_amdgcn_s_setprio(0);                           \
    __builtin_amdgcn_s_barrier();                            \
    asm volatile("" ::: "memory")

#define WAIT_VN()                                                          \
    do {                                                                   \
        if constexpr (NF == 2) asm volatile("s_waitcnt vmcnt(2)" ::: "memory"); \
        else if constexpr (NF == 3) asm volatile("s_waitcnt vmcnt(3)" ::: "memory"); \
        else asm volatile("s_waitcnt vmcnt(4)" ::: "memory");              \
    } while (0)

#define PHASE_END_VN()                                       \
    __builtin_amdgcn_s_setprio(0);                           \
    WAIT_VN();                                               \
    __builtin_amdgcn_s_barrier();                            \
    asm volatile("" ::: "memory")

template <int MODE, int NF>
__global__ __launch_bounds__(512, 2) void gemm256(
    const unsigned short* __restrict__ A, const unsigned short* __restrict__ B,
    const float* __restrict__ bias, unsigned short* __restrict__ Cb,
    float* __restrict__ Cf, int M, int N, int K, int NBN, int halfN, int half_elems) {
    constexpr int BN = NF * 64;
    __shared__ unsigned short lds[2][16384 + NF * 4096];  // [buf][A 32KB | B NF*8KB]
    const int tid = threadIdx.x;
    const int wv = tid >> 6, ln = tid & 63;
    const int fr = ln & 15, fo = ln >> 4;
    const int wr = wv >> 2, wc = wv & 3;
    // XCD-aware swizzle (gridDim.x % 8 == 0 for all call sites)
    const int cpx = gridDim.x >> 3;
    const int wgid = (blockIdx.x & 7) * cpx + (blockIdx.x >> 3);
    const int bm = wgid / NBN, bn = wgid % NBN;
    const unsigned short* Abase = A + (size_t)(bm * 256) * K;
    const unsigned short* Bbase = B + (size_t)(bn * BN) * K;
    const int NT = K >> 6;
    const int NI = NT >> 1;

    auto stagePair = [&](int buf, int isB, int t) {
        const unsigned short* G = isB ? Bbase : Abase;
        unsigned short* Ld = &lds[buf][isB ? 16384 : 0];
        const int kcol = t * 64;
        const int nch = isB ? NF : 4;
        #pragma unroll
        for (int r2 = 0; r2 < nch; ++r2) {
            int d = r2 * 8192 + wv * 1024 + ln * 16;        // linear dest byte
            int sw = d ^ (((d >> 7) & 7) << 4);             // pre-swizzled source
            int grow = sw >> 7;
            int gcol = (sw & 127) >> 1;
            gload_lds16(G + (size_t)grow * K + kcol + gcol,
                        (char*)Ld + r2 * 8192 + wv * 1024);
        }
    };
    auto readA = [&](int buf, int mh, int ks, short8* dst) {
        #pragma unroll
        for (int m = 0; m < 4; ++m) {
            int row = wr * 128 + mh * 64 + m * 16 + fr;
            int byte = (row * 128 + ks * 64 + fo * 16) ^ ((row & 7) << 4);
            dst[m] = *(const short8*)((const char*)&lds[buf][0] + byte);
        }
    };
    auto readB = [&](int buf, int ks, short8* dst) {
        #pragma unroll
        for (int n = 0; n < NF; ++n) {
            int row = wc * (NF * 16) + n * 16 + fr;
            int byte = (row * 128 + ks * 64 + fo * 16) ^ ((row & 7) << 4);
            dst[n] = *(const short8*)((const char*)&lds[buf][16384] + byte);
        }
    };

    f32x4 acc[8][NF];
    #pragma unroll
    for (int m = 0; m < 8; ++m)
        #pragma unroll
        for (int n = 0; n < NF; ++n) acc[m][n] = f32x4{0.f, 0.f, 0.f, 0.f};

    // prologue: buf0 <- tile0 (A+B), buf1.B <- tile1
    stagePair(0, 0, 0);
    stagePair(0, 1, 0);
    stagePair(1, 1, 1);
    WAIT_VN();
    __builtin_amdgcn_s_barrier();
    asm volatile("" ::: "memory");

    for (int i = 0; i < NI; ++i) {
        const int t1 = 2 * i + 1;
        const int tn0 = (2 * i + 2) % NT;
        const int tn1 = (2 * i + 3) % NT;
        short8 af[4], bf[4];
        // p0: compute buf0 (mh0,ks0); stage buf1.A <- t1 (used at p4)
        readA(0, 0, 0, af); readB(0, 0, bf);
        stagePair(1, 0, t1);
        PHASE_PRE(); MFMA_TILE(0); PHASE_END();
        // p1: (mh1,ks0)
        readA(0, 1, 0, af);
        PHASE_PRE(); MFMA_TILE(4); PHASE_END();
        // p2: (mh0,ks1)
        readA(0, 0, 1, af); readB(0, 1, bf);
        PHASE_PRE(); MFMA_TILE(0); PHASE_END();
        // p3: (mh1,ks1); stage buf0.B <- tn0; drain prev buf1.B + p0's buf1.A
        readA(0, 1, 1, af);
        stagePair(0, 1, tn0);
        PHASE_PRE(); MFMA_TILE(4); PHASE_END_VN();
        // p4: compute buf1 (mh0,ks0); stage buf0.A <- tn0
        readA(1, 0, 0, af); readB(1, 0, bf);
        stagePair(0, 0, tn0);
        PHASE_PRE(); MFMA_TILE(0); PHASE_END();
        // p5: (mh1,ks0)
        readA(1, 1, 0, af);
        PHASE_PRE(); MFMA_TILE(4); PHASE_END();
        // p6: (mh0,ks1)
        readA(1, 0, 1, af); readB(1, 1, bf);
        PHASE_PRE(); MFMA_TILE(0); PHASE_END();
        // p7: (mh1,ks1); stage buf1.B <- tn1; drain p3's buf0.B + p4's buf0.A
        readA(1, 1, 1, af);
        stagePair(1, 1, tn1);
        PHASE_PRE(); MFMA_TILE(4); PHASE_END_VN();
    }

    #pragma unroll
    for (int mi = 0; mi < 8; ++mi)
        #pragma unroll
        for (int ni = 0; ni < NF; ++ni)
            #pragma unroll
            for (int j = 0; j < 4; ++j) {
                int gr = bm * 256 + wr * 128 + mi * 16 + fo * 4 + j;
                int gc = bn * BN + wc * (NF * 16) + ni * 16 + fr;
                float v = acc[mi][ni][j] + bias[gc];
                if (MODE == 0) {
                    Cb[(size_t)gr * N + gc] = f2bf(v);
                } else {
                    if (gc < halfN) Cf[(size_t)gr * halfN + gc] = v;
                    else Cf[half_elems + (size_t)gr * halfN + (gc - halfN)] = v;
                }
            }
}

// ---------------------------------------------------------------- V transpose
// Vt[s][b][dcol][krow] <- qkv[b*2048+krow][2048 + s*512 + dcol]
__global__ __launch_bounds__(256) void transpose_v_k(
    const unsigned short* __restrict__ qkv, unsigned short* __restrict__ Vt) {
    int idx = blockIdx.x;
    int kt = idx & 31; idx >>= 5;
    int dt = idx & 7;  idx >>= 3;
    int b  = idx & 3;  idx >>= 2;
    int s  = idx;
    __shared__ unsigned short tile[64][65];
    int t = threadIdx.x;
    int r = t >> 2;
    int cs = (t & 3) * 16;
    const unsigned short* src =
        qkv + (size_t)(b * 2048 + kt * 64 + r) * 3072 + 2048 + s * 512 + dt * 64 + cs;
    short8 v0 = *(const short8*)src;
    short8 v1 = *(const short8*)(src + 8);
    #pragma unroll
    for (int i = 0; i < 8; ++i) { tile[r][cs + i] = v0[i]; tile[r][cs + 8 + i] = v1[i]; }
    __syncthreads();
    short8 o0, o1;
    #pragma unroll
    for (int i = 0; i < 8; ++i) { o0[i] = tile[cs + i][r]; o1[i] = tile[cs + 8 + i][r]; }
    unsigned short* dst =
        Vt + (size_t)((s * 4 + b) * 512 + dt * 64 + r) * 2048 + kt * 64 + cs;
    *(short8*)dst = o0;
    *(short8*)(dst + 8) = o1;
}

// ---------------------------------------------------------------- attention
// One 64-thread WG per (b, s, qb, quarter16, dhalf256): 2048 WGs. All loops
// FULLY unrolled (static register indexing — rule #20). QK^T runs in two
// d-halves with Q fragments reloaded per half (live qf 32 VGPR) so total
// pressure fits 256 VGPR -> 2 waves/SIMD (launch_bounds(64,2)).
__global__ __launch_bounds__(64, 2) void attn_k(
    const unsigned short* __restrict__ qkv, const unsigned short* __restrict__ Vt,
    unsigned short* __restrict__ attn, const int* __restrict__ nact,
    const unsigned char* __restrict__ lists) {
    int wg = blockIdx.x;
    int xcd = wg & 7, idx = wg >> 3;          // XCD holds one (b,s) K/V set
    int b = xcd >> 1, s = xcd & 1;
    int qb = idx >> 3, quarter = (idx >> 1) & 3, dh = idx & 1;
    int lane = threadIdx.x;
    int fr = lane & 15, fo = lane >> 4;
    const float scale = 0.04419417382415922f;  // 1/sqrt(512)
    __shared__ unsigned short Pl[1024];
    unsigned char* Plb = (unsigned char*)&Pl[0];

    int qoff = s * 512, koff = 1024 + s * 512;
    size_t vtbase = (size_t)((s * 4 + b) * 512 + dh * 256) * 2048;
    int mrow = b * 2048 + qb * 64 + quarter * 16;

    const unsigned short* qrow_ptr = qkv + (size_t)(mrow + fr) * 3072 + qoff + fo * 8;

    f32x4 acc[16];
    #pragma unroll
    for (int di = 0; di < 16; ++di) acc[di] = f32x4{0.f, 0.f, 0.f, 0.f};
    float mr[4] = {-1e30f, -1e30f, -1e30f, -1e30f};
    float lr[4] = {0.f, 0.f, 0.f, 0.f};

    int na = nact[s * 32 + qb];
    const unsigned char* lst = lists + (s * 32 + qb) * 32;

    for (int t = 0; t < na; ++t) {
        int kb = lst[t];
        const unsigned short* kbp =
            qkv + (size_t)(b * 2048 + kb * 64 + fr) * 3072 + koff + fo * 8;
        f32x4 sf[4];
        #pragma unroll
        for (int nf = 0; nf < 4; ++nf) sf[nf] = f32x4{0.f, 0.f, 0.f, 0.f};
        // QK^T in two d-halves; Q fragments reloaded per half (L1/L2-resident)
        #pragma unroll
        for (int h = 0; h < 2; ++h) {
            short8 qh[8];
            #pragma unroll
            for (int kk = 0; kk < 8; ++kk)
                qh[kk] = *(const short8*)(qrow_ptr + (h * 8 + kk) * 32);
            #pragma unroll
            for (int kk = 0; kk < 8; ++kk) {
                int kc = (h * 8 + kk) * 32;
                short8 k0 = *(const short8*)(kbp + kc);
                short8 k1 = *(const short8*)(kbp + (size_t)16 * 3072 + kc);
                short8 k2 = *(const short8*)(kbp + (size_t)32 * 3072 + kc);
                short8 k3 = *(const short8*)(kbp + (size_t)48 * 3072 + kc);
                sf[0] = __builtin_amdgcn_mfma_f32_16x16x32_bf16(qh[kk], k0, sf[0], 0, 0, 0);
                sf[1] = __builtin_amdgcn_mfma_f32_16x16x32_bf16(qh[kk], k1, sf[1], 0, 0, 0);
                sf[2] = __builtin_amdgcn_mfma_f32_16x16x32_bf16(qh[kk], k2, sf[2], 0, 0, 0);
                sf[3] = __builtin_amdgcn_mfma_f32_16x16x32_bf16(qh[kk], k3, sf[3], 0, 0, 0);
            }
        }
        #pragma unroll
        for (int nf = 0; nf < 4; ++nf) sf[nf] *= scale;
        float bm[4], f_[4], rs[4];
        #pragma unroll
        for (int j = 0; j < 4; ++j) {
            float v = fmaxf(fmaxf(sf[0][j], sf[1][j]), fmaxf(sf[2][j], sf[3][j]));
            #pragma unroll
            for (int off = 1; off < 16; off <<= 1) v = fmaxf(v, __shfl_xor(v, off, 64));
            bm[j] = v;
        }
        #pragma unroll
        for (int j = 0; j < 4; ++j) {
            float mn = fmaxf(mr[j], bm[j]);
            f_[j] = __expf(mr[j] - mn);
            mr[j] = mn;
            rs[j] = 0.f;
        }
        #pragma unroll
        for (int nf = 0; nf < 4; ++nf)
            #pragma unroll
            for (int j = 0; j < 4; ++j) {
                float p = __expf(sf[nf][j] - mr[j]);
                sf[nf][j] = p;
                rs[j] += p;
            }
        #pragma unroll
        for (int j = 0; j < 4; ++j) {
            float v = rs[j];
            #pragma unroll
            for (int off = 1; off < 16; off <<= 1) v += __shfl_xor(v, off, 64);
            lr[j] = lr[j] * f_[j] + v;
        }
        #pragma unroll
        for (int di = 0; di < 16; ++di) {
            acc[di][0] *= f_[0]; acc[di][1] *= f_[1];
            acc[di][2] *= f_[2]; acc[di][3] *= f_[3];
        }
        // P -> LDS (bf16), XOR-swizzled
        #pragma unroll
        for (int nf = 0; nf < 4; ++nf)
            #pragma unroll
            for (int j = 0; j < 4; ++j) {
                int row = fo * 4 + j, col = nf * 16 + fr;
                int byte = row * 128 + ((col * 2) ^ ((row & 7) << 4));
                *(unsigned short*)(Plb + byte) = f2bf(sf[nf][j]);
            }
        asm volatile("s_waitcnt lgkmcnt(0)" ::: "memory");
        // PV over this wave's 256 d-cols (fully unrolled, static indexing)
        #pragma unroll
        for (int ks = 0; ks < 2; ++ks) {
            int rbyte = fr * 128 + (((ks * 32 + fo * 8) * 2) ^ ((fr & 7) << 4));
            short8 pf = *(const short8*)(Plb + rbyte);
            const unsigned short* vp =
                Vt + vtbase + (size_t)fr * 2048 + kb * 64 + ks * 32 + fo * 8;
            #pragma unroll
            for (int di = 0; di < 16; ++di) {
                short8 vf = *(const short8*)(vp + (size_t)di * 16 * 2048);
                acc[di] = __builtin_amdgcn_mfma_f32_16x16x32_bf16(pf, vf, acc[di], 0, 0, 0);
            }
        }
    }
    float inv[4];
    #pragma unroll
    for (int j = 0; j < 4; ++j) inv[j] = 1.0f / lr[j];
    unsigned short* orow = attn + (size_t)(mrow + fo * 4) * 1024 + s * 512 + dh * 256 + fr;
    #pragma unroll
    for (int di = 0; di < 16; ++di)
        #pragma unroll
        for (int j = 0; j < 4; ++j)
            orow[(size_t)j * 1024 + di * 16] = f2bf(acc[di][j] * inv[j]);
}

// ---------------------------------------------------------------- launch
extern "C" void kernel_launch(void* const* d_in, const int* in_sizes, int n_in,
                              void* d_out, int out_size, void* d_ws, size_t ws_size,
                              hipStream_t stream) {
    const float* q_r = (const float*)d_in[0];
    const float* q_i = (const float*)d_in[1];
    const float* k_r = (const float*)d_in[2];
    const float* k_i = (const float*)d_in[3];
    const float* v_r = (const float*)d_in[4];
    const float* v_i = (const float*)d_in[5];
    const float* W_qkv = (const float*)d_in[6];
    const float* b_qkv = (const float*)d_in[7];
    const float* W_out = (const float*)d_in[8];
    const float* b_out = (const float*)d_in[9];
    const void* mask_r = d_in[10];
    const void* mask_i = d_in[11];

    char* ws = (char*)d_ws;
    unsigned short* x    = (unsigned short*)(ws);                  // 50331648 B
    unsigned short* Wq   = (unsigned short*)(ws + 50331648);       // 18874368 B
    unsigned short* qkv  = (unsigned short*)(ws + 69206016);       // 50331648 B
    unsigned short* Wo   = (unsigned short*)(ws + 119537664);      //  2097152 B
    int* nact            = (int*)(ws + 121634816);                 //   256 B
    unsigned char* lists = (unsigned char*)(ws + 121634816 + 256); //  2048 B
    // x region is dead after GEMM1 -> reuse for Vt and attn
    unsigned short* Vt   = x;                                      // 16777216 B
    unsigned short* attn = x + 8388608;                            // 16777216 B

    f32_to_bf16_k<<<4608, 256, 0, stream>>>(W_qkv, Wq, 1179648);
    f32_to_bf16_k<<<512, 256, 0, stream>>>(W_out, Wo, 131072);
    pack_x_k<<<12288, 256, 0, stream>>>(q_r, q_i, k_r, k_i, v_r, v_i, x);
    scan_masks_k<<<64, 64, 0, stream>>>(mask_r, mask_i, nact, lists);
    gemm256<0, 3><<<512, 512, 0, stream>>>(x, Wq, b_qkv, qkv, nullptr,
                                           8192, 3072, 3072, 16, 0, 0);
    transpose_v_k<<<2048, 256, 0, stream>>>(qkv, Vt);
    attn_k<<<2048, 64, 0, stream>>>(qkv, Vt, attn, nact, lists);
    gemm256<1, 2><<<256, 512, 0, stream>>>(attn, Wo, b_out, nullptr, (float*)d_out,
                                           8192, 1024, 1024, 8, 512, 4194304);
}

// Round 8
// 468.876 us; speedup vs baseline: 1.2634x; 1.0125x over previous
//
#include <hip/hip_runtime.h>
#include <stdint.h>

typedef __attribute__((ext_vector_type(8))) short short8;
typedef __attribute__((ext_vector_type(4))) float f32x4;

#define DEV __device__ __forceinline__

DEV unsigned short f2bf(float f) {
    unsigned int u = __float_as_uint(f);
    u += 0x7FFFu + ((u >> 16) & 1u);   // round-to-nearest-even
    return (unsigned short)(u >> 16);
}

DEV void gload_lds16(const void* g, void* l) {
    // async global->LDS, 16B per lane. LDS dest is wave-uniform base (+lane*16 by HW).
    __builtin_amdgcn_global_load_lds(
        (const __attribute__((address_space(1))) unsigned int*)g,
        (__attribute__((address_space(3))) unsigned int*)l,
        16, 0, 0);
}

// ---------------------------------------------------------------- converts
__global__ __launch_bounds__(256) void f32_to_bf16_k(
    const float* __restrict__ in, unsigned short* __restrict__ out, int n8) {
    int i = blockIdx.x * 256 + threadIdx.x;
    if (i >= n8) return;
    const float4* src = (const float4*)in + (size_t)i * 2;
    float4 a = src[0], b = src[1];
    short8 o;
    o[0] = f2bf(a.x); o[1] = f2bf(a.y); o[2] = f2bf(a.z); o[3] = f2bf(a.w);
    o[4] = f2bf(b.x); o[5] = f2bf(b.y); o[6] = f2bf(b.z); o[7] = f2bf(b.w);
    *((short8*)out + i) = o;
}

// build x_bf16 [8192][3072] from the six [4,2048,512] f32 inputs
// one block per output row; sel is wave-uniform (64 threads x 8 elems = 512)
__global__ __launch_bounds__(384) void pack_x_k(
    const float* __restrict__ p0, const float* __restrict__ p1,
    const float* __restrict__ p2, const float* __restrict__ p3,
    const float* __restrict__ p4, const float* __restrict__ p5,
    unsigned short* __restrict__ x) {
    int m = blockIdx.x;             // 8192 rows
    int t = threadIdx.x;            // 384 threads -> 3072 elems
    int k = t * 8;
    int sel = k >> 9;
    const float* src;
    switch (sel) {
        case 0: src = p0; break; case 1: src = p1; break;
        case 2: src = p2; break; case 3: src = p3; break;
        case 4: src = p4; break; default: src = p5; break;
    }
    src += (size_t)m * 512 + (k & 511);
    float4 a = *(const float4*)src;
    float4 b = *(const float4*)(src + 4);
    short8 o;
    o[0] = f2bf(a.x); o[1] = f2bf(a.y); o[2] = f2bf(a.z); o[3] = f2bf(a.w);
    o[4] = f2bf(b.x); o[5] = f2bf(b.y); o[6] = f2bf(b.z); o[7] = f2bf(b.w);
    *(short8*)(x + (size_t)m * 3072 + k) = o;
}

// ---------------------------------------------------------------- mask scan
__global__ void scan_masks_k(const void* mr, const void* mi,
                             int* __restrict__ nact, unsigned char* __restrict__ lists) {
    int blk = blockIdx.x;            // 64 = 2 streams x 32 qb
    int s = blk >> 5, qb = blk & 31;
    int lane = threadIdx.x;
    const unsigned char* det = (const unsigned char*)mr;
    bool is_byte = det[1] != 0;      // bool-byte vs 4-byte storage
    const void* m = s ? mi : mr;
    bool on = false;
    if (lane < 32) {
        size_t off = (size_t)(qb * 64) * 2048 + (size_t)lane * 64;
        on = is_byte ? (((const unsigned char*)m)[off] != 0)
                     : (((const int*)m)[off] != 0);
    }
    unsigned long long mask = __ballot(on);
    if (on) {
        int pos = __popcll(mask & ((1ull << lane) - 1ull));
        lists[blk * 32 + pos] = (unsigned char)lane;
    }
    if (lane == 0) nact[blk] = (int)__popcll(mask);
}

// ---------------------------------------------------------------- 4-phase GEMM (B^T)
// C[m,n] = sum_k A[m,k]*B[n,k] + bias[n].  BM=256, BN=NF*64, BK=64,
// 512 threads (8 waves, 2Mx4N; wave tile 128 x NF*16). 2 K-tiles/iter,
// 4 phases of 8xNF MFMA each (amortize ds-wait+barriers over 2x MFMA).
// Phase X reads {all 8 m-frags + NF n-frags} for one k-step. Stages:
// pA: buf1.A(t1), pB: buf1.B(t1) + vmcnt(0), pC: buf0.A(tn0), pD: buf0.B(tn0)
// + vmcnt(0). Every stage issues >=1 barrier after its buffer's last reader
// drained; every read follows a vmcnt(0) of stages issued >=1 phase earlier.
// LDS st-swizzle byte ^= ((row&7)<<4) on BOTH pre-swizzled global source of
// global_load_lds and the ds_read address (rule 21).

#define MFMA_ALL()                                                             \
    do {                                                                       \
        _Pragma("unroll")                                                      \
        for (int m_ = 0; m_ < 8; ++m_) {                                       \
            _Pragma("unroll")                                                  \
            for (int n_ = 0; n_ < NF; ++n_)                                    \
                acc[m_][n_] = __builtin_amdgcn_mfma_f32_16x16x32_bf16(         \
                    a8[m_], b8[n_], acc[m_][n_], 0, 0, 0);                     \
        }                                                                      \
    } while (0)

#define PHASE_PRE()                                          \
    __builtin_amdgcn_s_barrier();                            \
    asm volatile("s_waitcnt lgkmcnt(0)" ::: "memory");       \
    __builtin_amdgcn_sched_barrier(0);                       \
    __builtin_amdgcn_s_setprio(1)

#define PHASE_END()                                          \
    __builtin_amdgcn_s_setprio(0);                           \
    __builtin_amdgcn_s_barrier();                            \
    asm volatile("" ::: "memory")

#define PHASE_END_V0()                                       \
    __builtin_amdgcn_s_setprio(0);                           \
    asm volatile("s_waitcnt vmcnt(0)" ::: "memory");         \
    __builtin_amdgcn_s_barrier();                            \
    asm volatile("" ::: "memory")

template <int MODE, int NF>
__global__ __launch_bounds__(512, 2) void gemm256(
    const unsigned short* __restrict__ A, const unsigned short* __restrict__ B,
    const float* __restrict__ bias, unsigned short* __restrict__ Cb,
    float* __restrict__ Cf, int M, int N, int K, int NBN, int halfN, int half_elems) {
    constexpr int BN = NF * 64;
    __shared__ unsigned short lds[2][16384 + NF * 4096];  // [buf][A 32KB | B NF*8KB]
    const int tid = threadIdx.x;
    const int wv = tid >> 6, ln = tid & 63;
    const int fr = ln & 15, fo = ln >> 4;
    const int wr = wv >> 2, wc = wv & 3;
    // XCD-aware swizzle (gridDim.x % 8 == 0 for all call sites)
    const int cpx = gridDim.x >> 3;
    const int wgid = (blockIdx.x & 7) * cpx + (blockIdx.x >> 3);
    const int bm = wgid / NBN, bn = wgid % NBN;
    const unsigned short* Abase = A + (size_t)(bm * 256) * K;
    const unsigned short* Bbase = B + (size_t)(bn * BN) * K;
    const int NT = K >> 6;
    const int NI = NT >> 1;

    // stage half: isB=0 -> A rows (4 chunks), isB=1 -> B rows (NF chunks)
    auto stageHalf = [&](int buf, int isB, int t) {
        const unsigned short* G = isB ? Bbase : Abase;
        unsigned short* Ld = &lds[buf][isB ? 16384 : 0];
        const int kcol = t * 64;
        const int nch = isB ? NF : 4;
        #pragma unroll
        for (int r2 = 0; r2 < nch; ++r2) {
            int d = r2 * 8192 + wv * 1024 + ln * 16;        // linear dest byte
            int sw = d ^ (((d >> 7) & 7) << 4);             // pre-swizzled source
            int grow = sw >> 7;
            int gcol = (sw & 127) >> 1;
            gload_lds16(G + (size_t)grow * K + kcol + gcol,
                        (char*)Ld + r2 * 8192 + wv * 1024);
        }
    };
    // read full k-step: 8 A-frags (both mh) + NF B-frags
    auto readAB = [&](int buf, int ks, short8* a8, short8* b8) {
        #pragma unroll
        for (int m = 0; m < 8; ++m) {
            int row = wr * 128 + m * 16 + fr;
            int byte = (row * 128 + ks * 64 + fo * 16) ^ ((row & 7) << 4);
            a8[m] = *(const short8*)((const char*)&lds[buf][0] + byte);
        }
        #pragma unroll
        for (int n = 0; n < NF; ++n) {
            int row = wc * (NF * 16) + n * 16 + fr;
            int byte = (row * 128 + ks * 64 + fo * 16) ^ ((row & 7) << 4);
            b8[n] = *(const short8*)((const char*)&lds[buf][16384] + byte);
        }
    };

    f32x4 acc[8][NF];
    #pragma unroll
    for (int m = 0; m < 8; ++m)
        #pragma unroll
        for (int n = 0; n < NF; ++n) acc[m][n] = f32x4{0.f, 0.f, 0.f, 0.f};

    // prologue: buf0 <- tile0 (A+B), drain, barrier
    stageHalf(0, 0, 0);
    stageHalf(0, 1, 0);
    asm volatile("s_waitcnt vmcnt(0)" ::: "memory");
    __builtin_amdgcn_s_barrier();
    asm volatile("" ::: "memory");

    for (int i = 0; i < NI; ++i) {
        const int t1 = 2 * i + 1;
        const int tn0 = (2 * i + 2) % NT;
        short8 a8[8], b8[NF];
        // pA: compute buf0 ks0; stage buf1.A <- t1
        readAB(0, 0, a8, b8);
        stageHalf(1, 0, t1);
        PHASE_PRE(); MFMA_ALL(); PHASE_END();
        // pB: compute buf0 ks1; stage buf1.B <- t1; drain (pA+pB stages)
        readAB(0, 1, a8, b8);
        stageHalf(1, 1, t1);
        PHASE_PRE(); MFMA_ALL(); PHASE_END_V0();
        // pC: compute buf1 ks0; stage buf0.A <- tn0
        readAB(1, 0, a8, b8);
        stageHalf(0, 0, tn0);
        PHASE_PRE(); MFMA_ALL(); PHASE_END();
        // pD: compute buf1 ks1; stage buf0.B <- tn0; drain (pC+pD stages)
        readAB(1, 1, a8, b8);
        stageHalf(0, 1, tn0);
        PHASE_PRE(); MFMA_ALL(); PHASE_END_V0();
    }

    #pragma unroll
    for (int mi = 0; mi < 8; ++mi)
        #pragma unroll
        for (int ni = 0; ni < NF; ++ni)
            #pragma unroll
            for (int j = 0; j < 4; ++j) {
                int gr = bm * 256 + wr * 128 + mi * 16 + fo * 4 + j;
                int gc = bn * BN + wc * (NF * 16) + ni * 16 + fr;
                float v = acc[mi][ni][j] + bias[gc];
                if (MODE == 0) {
                    Cb[(size_t)gr * N + gc] = f2bf(v);
                } else {
                    if (gc < halfN) Cf[(size_t)gr * halfN + gc] = v;
                    else Cf[half_elems + (size_t)gr * halfN + (gc - halfN)] = v;
                }
            }
}

// ---------------------------------------------------------------- V transpose
// Vt[s][b][dcol][krow] <- qkv[b*2048+krow][2048 + s*512 + dcol]
__global__ __launch_bounds__(256) void transpose_v_k(
    const unsigned short* __restrict__ qkv, unsigned short* __restrict__ Vt) {
    int idx = blockIdx.x;
    int kt = idx & 31; idx >>= 5;
    int dt = idx & 7;  idx >>= 3;
    int b  = idx & 3;  idx >>= 2;
    int s  = idx;
    __shared__ unsigned short tile[64][65];
    int t = threadIdx.x;
    int r = t >> 2;
    int cs = (t & 3) * 16;
    const unsigned short* src =
        qkv + (size_t)(b * 2048 + kt * 64 + r) * 3072 + 2048 + s * 512 + dt * 64 + cs;
    short8 v0 = *(const short8*)src;
    short8 v1 = *(const short8*)(src + 8);
    #pragma unroll
    for (int i = 0; i < 8; ++i) { tile[r][cs + i] = v0[i]; tile[r][cs + 8 + i] = v1[i]; }
    __syncthreads();
    short8 o0, o1;
    #pragma unroll
    for (int i = 0; i < 8; ++i) { o0[i] = tile[cs + i][r]; o1[i] = tile[cs + 8 + i][r]; }
    unsigned short* dst =
        Vt + (size_t)((s * 4 + b) * 512 + dt * 64 + r) * 2048 + kt * 64 + cs;
    *(short8*)dst = o0;
    *(short8*)(dst + 8) = o1;
}

// ---------------------------------------------------------------- attention
// One 64-thread WG per (b, s, qb, quarter16, dhalf256): 2048 WGs. All loops
// FULLY unrolled (static register indexing — rule #20). QK^T runs in two
// d-halves with Q fragments reloaded per half (live qf 32 VGPR) so total
// pressure fits 256 VGPR -> 2 waves/SIMD (launch_bounds(64,2)).
__global__ __launch_bounds__(64, 2) void attn_k(
    const unsigned short* __restrict__ qkv, const unsigned short* __restrict__ Vt,
    unsigned short* __restrict__ attn, const int* __restrict__ nact,
    const unsigned char* __restrict__ lists) {
    int wg = blockIdx.x;
    int xcd = wg & 7, idx = wg >> 3;          // XCD holds one (b,s) K/V set
    int b = xcd >> 1, s = xcd & 1;
    int qb = idx >> 3, quarter = (idx >> 1) & 3, dh = idx & 1;
    int lane = threadIdx.x;
    int fr = lane & 15, fo = lane >> 4;
    const float scale = 0.04419417382415922f;  // 1/sqrt(512)
    __shared__ unsigned short Pl[1024];
    unsigned char* Plb = (unsigned char*)&Pl[0];

    int qoff = s * 512, koff = 1024 + s * 512;
    size_t vtbase = (size_t)((s * 4 + b) * 512 + dh * 256) * 2048;
    int mrow = b * 2048 + qb * 64 + quarter * 16;

    const unsigned short* qrow_ptr = qkv + (size_t)(mrow + fr) * 3072 + qoff + fo * 8;

    f32x4 acc[16];
    #pragma unroll
    for (int di = 0; di < 16; ++di) acc[di] = f32x4{0.f, 0.f, 0.f, 0.f};
    float mr[4] = {-1e30f, -1e30f, -1e30f, -1e30f};
    float lr[4] = {0.f, 0.f, 0.f, 0.f};

    int na = nact[s * 32 + qb];
    const unsigned char* lst = lists + (s * 32 + qb) * 32;

    for (int t = 0; t < na; ++t) {
        int kb = lst[t];
        const unsigned short* kbp =
            qkv + (size_t)(b * 2048 + kb * 64 + fr) * 3072 + koff + fo * 8;
        f32x4 sf[4];
        #pragma unroll
        for (int nf = 0; nf < 4; ++nf) sf[nf] = f32x4{0.f, 0.f, 0.f, 0.f};
        // QK^T in two d-halves; Q fragments reloaded per half (L1/L2-resident)
        #pragma unroll
        for (int h = 0; h < 2; ++h) {
            short8 qh[8];
            #pragma unroll
            for (int kk = 0; kk < 8; ++kk)
                qh[kk] = *(const short8*)(qrow_ptr + (h * 8 + kk) * 32);
            #pragma unroll
            for (int kk = 0; kk < 8; ++kk) {
                int kc = (h * 8 + kk) * 32;
                short8 k0 = *(const short8*)(kbp + kc);
                short8 k1 = *(const short8*)(kbp + (size_t)16 * 3072 + kc);
                short8 k2 = *(const short8*)(kbp + (size_t)32 * 3072 + kc);
                short8 k3 = *(const short8*)(kbp + (size_t)48 * 3072 + kc);
                sf[0] = __builtin_amdgcn_mfma_f32_16x16x32_bf16(qh[kk], k0, sf[0], 0, 0, 0);
                sf[1] = __builtin_amdgcn_mfma_f32_16x16x32_bf16(qh[kk], k1, sf[1], 0, 0, 0);
                sf[2] = __builtin_amdgcn_mfma_f32_16x16x32_bf16(qh[kk], k2, sf[2], 0, 0, 0);
                sf[3] = __builtin_amdgcn_mfma_f32_16x16x32_bf16(qh[kk], k3, sf[3], 0, 0, 0);
            }
        }
        #pragma unroll
        for (int nf = 0; nf < 4; ++nf) sf[nf] *= scale;
        float bm[4], f_[4], rs[4];
        #pragma unroll
        for (int j = 0; j < 4; ++j) {
            float v = fmaxf(fmaxf(sf[0][j], sf[1][j]), fmaxf(sf[2][j], sf[3][j]));
            #pragma unroll
            for (int off = 1; off < 16; off <<= 1) v = fmaxf(v, __shfl_xor(v, off, 64));
            bm[j] = v;
        }
        #pragma unroll
        for (int j = 0; j < 4; ++j) {
            float mn = fmaxf(mr[j], bm[j]);
            f_[j] = __expf(mr[j] - mn);
            mr[j] = mn;
            rs[j] = 0.f;
        }
        #pragma unroll
        for (int nf = 0; nf < 4; ++nf)
            #pragma unroll
            for (int j = 0; j < 4; ++j) {
                float p = __expf(sf[nf][j] - mr[j]);
                sf[nf][j] = p;
                rs[j] += p;
            }
        #pragma unroll
        for (int j = 0; j < 4; ++j) {
            float v = rs[j];
            #pragma unroll
            for (int off = 1; off < 16; off <<= 1) v += __shfl_xor(v, off, 64);
            lr[j] = lr[j] * f_[j] + v;
        }
        #pragma unroll
        for (int di = 0; di < 16; ++di) {
            acc[di][0] *= f_[0]; acc[di][1] *= f_[1];
            acc[di][2] *= f_[2]; acc[di][3] *= f_[3];
        }
        // P -> LDS (bf16), XOR-swizzled
        #pragma unroll
        for (int nf = 0; nf < 4; ++nf)
            #pragma unroll
            for (int j = 0; j < 4; ++j) {
                int row = fo * 4 + j, col = nf * 16 + fr;
                int byte = row * 128 + ((col * 2) ^ ((row & 7) << 4));
                *(unsigned short*)(Plb + byte) = f2bf(sf[nf][j]);
            }
        asm volatile("s_waitcnt lgkmcnt(0)" ::: "memory");
        // PV over this wave's 256 d-cols (fully unrolled, static indexing)
        #pragma unroll
        for (int ks = 0; ks < 2; ++ks) {
            int rbyte = fr * 128 + (((ks * 32 + fo * 8) * 2) ^ ((fr & 7) << 4));
            short8 pf = *(const short8*)(Plb + rbyte);
            const unsigned short* vp =
                Vt + vtbase + (size_t)fr * 2048 + kb * 64 + ks * 32 + fo * 8;
            #pragma unroll
            for (int di = 0; di < 16; ++di) {
                short8 vf = *(const short8*)(vp + (size_t)di * 16 * 2048);
                acc[di] = __builtin_amdgcn_mfma_f32_16x16x32_bf16(pf, vf, acc[di], 0, 0, 0);
            }
        }
    }
    float inv[4];
    #pragma unroll
    for (int j = 0; j < 4; ++j) inv[j] = 1.0f / lr[j];
    unsigned short* orow = attn + (size_t)(mrow + fo * 4) * 1024 + s * 512 + dh * 256 + fr;
    #pragma unroll
    for (int di = 0; di < 16; ++di)
        #pragma unroll
        for (int j = 0; j < 4; ++j)
            orow[(size_t)j * 1024 + di * 16] = f2bf(acc[di][j] * inv[j]);
}

// ---------------------------------------------------------------- launch
extern "C" void kernel_launch(void* const* d_in, const int* in_sizes, int n_in,
                              void* d_out, int out_size, void* d_ws, size_t ws_size,
                              hipStream_t stream) {
    const float* q_r = (const float*)d_in[0];
    const float* q_i = (const float*)d_in[1];
    const float* k_r = (const float*)d_in[2];
    const float* k_i = (const float*)d_in[3];
    const float* v_r = (const float*)d_in[4];
    const float* v_i = (const float*)d_in[5];
    const float* W_qkv = (const float*)d_in[6];
    const float* b_qkv = (const float*)d_in[7];
    const float* W_out = (const float*)d_in[8];
    const float* b_out = (const float*)d_in[9];
    const void* mask_r = d_in[10];
    const void* mask_i = d_in[11];

    char* ws = (char*)d_ws;
    unsigned short* x    = (unsigned short*)(ws);                  // 50331648 B
    unsigned short* Wq   = (unsigned short*)(ws + 50331648);       // 18874368 B
    unsigned short* qkv  = (unsigned short*)(ws + 69206016);       // 50331648 B
    unsigned short* Wo   = (unsigned short*)(ws + 119537664);      //  2097152 B
    int* nact            = (int*)(ws + 121634816);                 //   256 B
    unsigned char* lists = (unsigned char*)(ws + 121634816 + 256); //  2048 B
    // x region is dead after GEMM1 -> reuse for Vt and attn
    unsigned short* Vt   = x;                                      // 16777216 B
    unsigned short* attn = x + 8388608;                            // 16777216 B

    f32_to_bf16_k<<<4608, 256, 0, stream>>>(W_qkv, Wq, 1179648);
    f32_to_bf16_k<<<512, 256, 0, stream>>>(W_out, Wo, 131072);
    pack_x_k<<<8192, 384, 0, stream>>>(q_r, q_i, k_r, k_i, v_r, v_i, x);
    scan_masks_k<<<64, 64, 0, stream>>>(mask_r, mask_i, nact, lists);
    gemm256<0, 3><<<512, 512, 0, stream>>>(x, Wq, b_qkv, qkv, nullptr,
                                           8192, 3072, 3072, 16, 0, 0);
    transpose_v_k<<<2048, 256, 0, stream>>>(qkv, Vt);
    attn_k<<<2048, 64, 0, stream>>>(qkv, Vt, attn, nact, lists);
    gemm256<1, 2><<<256, 512, 0, stream>>>(attn, Wo, b_out, nullptr, (float*)d_out,
                                           8192, 1024, 1024, 8, 512, 4194304);
}